// Round 1
// 359.742 us; speedup vs baseline: 1.0537x; 1.0537x over previous
//
#include <hip/hip_runtime.h>

#define BB 8
#define HH 1024
#define WW 1024
#define HW (HH*WW)
#define PI_F 3.14159265358979323846f

static __device__ __forceinline__ int wrapm(int i, int n) { return (i == 0) ? n - 1 : i - 1; }
static __device__ __forceinline__ int wrapp(int i, int n) { return (i == n - 1) ? 0 : i + 1; }

// ---------------------------------------------------------------------------
// Twiddle table (global, computed once per launch): per-stage concatenated,
// stage with half-span len at offset (1024-2*len), len entries exp(-i*pi*j/len)
// ---------------------------------------------------------------------------
__global__ __launch_bounds__(256) void k_twid(float2* __restrict__ tw)
{
    int tid = blockIdx.x * 256 + threadIdx.x;   // grid 4x256 = 1024 threads
    for (int len = 512; len >= 1; len >>= 1) {
        int off = 1024 - 2 * len;
        float fac = -PI_F / (float)len;
        for (int j = tid; j < len; j += 1024) {
            float sn, cs;
            sincosf(fac * (float)j, &sn, &cs);
            tw[off + j] = make_float2(cs, sn);
        }
    }
}

// ---------------------------------------------------------------------------
// Fused 3x diffusion of f_u/f_v + L2 norm accumulation — quad-vectorized.
// Output tile 64x32. LDS tile 38 rows x 72 cols (halo: 4 left, 4 right, 3
// top, 3 bottom). Row stride is exactly 72 floats = 18 quads, so the tile is
// CONTIGUOUS in quad-linear order -> global_load_lds DMA staging and
// conflict-free ds_read_b128 (each wave touches 1024 contiguous LDS bytes).
// Column validity: loaded 0..71 valid; iter1 valid 1..70; iter2 valid 2..69;
// iter3 stores cols 4..67 (reads 3..68) -> exact. dst layout [f*8+b][HW].
// ---------------------------------------------------------------------------
#define TDX 64
#define TDY 32
#define LSTR 72          // floats per LDS row (= 18 quads, contiguous)
#define LROWS 38
#define NQ 684           // 38*18 quads in tile
#define NQPAD 704        // padded to a multiple of 64 (wave DMA chunk)

static __device__ __forceinline__ void gload16(const float* g, float* l)
{
    __builtin_amdgcn_global_load_lds(
        (const __attribute__((address_space(1))) void*)g,
        (__attribute__((address_space(3))) void*)l,
        16, 0, 0);
}

__global__ __launch_bounds__(256) void k_diff3(const float* __restrict__ su,
                                               const float* __restrict__ sv,
                                               float* __restrict__ dst,
                                               float* __restrict__ norms)
{
    __shared__ __align__(16) float A[NQPAD * 4];      // 2816 floats (incl. DMA pad)
    __shared__ __align__(16) float Bf[LROWS * LSTR];  // 2736 floats
    __shared__ float wsum[4];
    int z = blockIdx.z;            // f*8+b
    int f = z >> 3, b = z & 7;
    const float* s = ((f == 0) ? su : sv) + (size_t)b * HW;
    float* d = dst + (size_t)z * HW;
    int x0 = blockIdx.x * TDX - 4;   // local col 0 <-> global x0
    int y0 = blockIdx.y * TDY - 3;   // local row 0 <-> global y0
    int tid = threadIdx.x;
    int lane = tid & 63;

    // ---- stage tile: 11 wave-chunks of 64 contiguous quads each ----------
    for (int ch = tid >> 6; ch < 11; ch += 4) {
        int lin = (ch << 6) + lane;            // quad-linear index (tail -> pad)
        int r = lin / 18;
        int q = lin - r * 18;
        const float* g = s + (size_t)((y0 + r) & (HH - 1)) * WW
                           + ((x0 + (q << 2)) & (WW - 1));
        gload16(g, &A[lin << 2]);
    }
    __syncthreads();   // drains vmcnt(0)

    // ---- iter 1: A -> Bf, rows 1..36, all 18 quads ------------------------
    for (int t = tid; t < 648; t += 256) {
        int r = t / 18; int q = t - r * 18; r += 1;
        int idx = r * LSTR + (q << 2);
        float4 c  = *(const float4*)&A[idx];
        float4 up = *(const float4*)&A[idx - LSTR];
        float4 dn = *(const float4*)&A[idx + LSTR];
        float lf = __shfl_up(c.w, 1, 64);
        float rt = __shfl_down(c.x, 1, 64);
        if (lane == 0)  lf = A[idx - 1];
        if (lane == 63) rt = A[idx + 4];
        float4 o;
        o.x = c.x + 0.1f * (lf  + c.y + up.x + dn.x - 4.0f * c.x);
        o.y = c.y + 0.1f * (c.x + c.z + up.y + dn.y - 4.0f * c.y);
        o.z = c.z + 0.1f * (c.y + c.w + up.z + dn.z - 4.0f * c.z);
        o.w = c.w + 0.1f * (c.z + rt  + up.w + dn.w - 4.0f * c.w);
        *(float4*)&Bf[idx] = o;
    }
    __syncthreads();

    // ---- iter 2: Bf -> A, rows 2..35, all 18 quads ------------------------
    for (int t = tid; t < 612; t += 256) {
        int r = t / 18; int q = t - r * 18; r += 2;
        int idx = r * LSTR + (q << 2);
        float4 c  = *(const float4*)&Bf[idx];
        float4 up = *(const float4*)&Bf[idx - LSTR];
        float4 dn = *(const float4*)&Bf[idx + LSTR];
        float lf = __shfl_up(c.w, 1, 64);
        float rt = __shfl_down(c.x, 1, 64);
        if (lane == 0)  lf = Bf[idx - 1];
        if (lane == 63) rt = Bf[idx + 4];
        float4 o;
        o.x = c.x + 0.1f * (lf  + c.y + up.x + dn.x - 4.0f * c.x);
        o.y = c.y + 0.1f * (c.x + c.z + up.y + dn.y - 4.0f * c.y);
        o.z = c.z + 0.1f * (c.y + c.w + up.z + dn.z - 4.0f * c.z);
        o.w = c.w + 0.1f * (c.z + rt  + up.w + dn.w - 4.0f * c.w);
        *(float4*)&A[idx] = o;
    }
    __syncthreads();

    // ---- iter 3: A -> global, rows 3..34; store quads 1..16 (cols 4..67) --
    float sq = 0.0f;
    for (int t = tid; t < 576; t += 256) {
        int r = t / 18; int q = t - r * 18; r += 3;
        int idx = r * LSTR + (q << 2);
        float4 c  = *(const float4*)&A[idx];
        float4 up = *(const float4*)&A[idx - LSTR];
        float4 dn = *(const float4*)&A[idx + LSTR];
        float lf = __shfl_up(c.w, 1, 64);
        float rt = __shfl_down(c.x, 1, 64);
        if (lane == 0)  lf = A[idx - 1];
        if (lane == 63) rt = A[idx + 4];
        float4 o;
        o.x = c.x + 0.1f * (lf  + c.y + up.x + dn.x - 4.0f * c.x);
        o.y = c.y + 0.1f * (c.x + c.z + up.y + dn.y - 4.0f * c.y);
        o.z = c.z + 0.1f * (c.y + c.w + up.z + dn.z - 4.0f * c.z);
        o.w = c.w + 0.1f * (c.z + rt  + up.w + dn.w - 4.0f * c.w);
        if (q >= 1 && q <= 16) {
            *(float4*)(d + (size_t)(y0 + r) * WW + (x0 + (q << 2))) = o;
            sq += o.x * o.x + o.y * o.y + o.z * o.z + o.w * o.w;
        }
    }
    #pragma unroll
    for (int o = 32; o > 0; o >>= 1) sq += __shfl_down(sq, o, 64);
    int wid = tid >> 6;
    if (lane == 0) wsum[wid] = sq;
    __syncthreads();
    if (tid == 0)
        atomicAdd(&norms[z], wsum[0] + wsum[1] + wsum[2] + wsum[3]);
}

// ---------------------------------------------------------------------------
// Star velocities
// ---------------------------------------------------------------------------
__global__ __launch_bounds__(256) void k_star(const float* __restrict__ X,
                                              const float* __restrict__ beta,
                                              const float* __restrict__ F,
                                              const float* __restrict__ norms,
                                              float* __restrict__ UV)
{
    int b = blockIdx.z;
    int y = blockIdx.y;
    int x = blockIdx.x * 256 + threadIdx.x;
    const float* u = X + (size_t)(b * 3 + 0) * HW;
    const float* v = X + (size_t)(b * 3 + 1) * HW;
    const float* p = X + (size_t)(b * 3 + 2) * HW;
    int yr = y * WW, ym = wrapm(y, HH) * WW, yp = wrapp(y, HH) * WW;
    int xm = wrapm(x, WW), xp = wrapp(x, WW);

    float uc = u[yr + x], ul = u[yr + xm], ur = u[yr + xp], uu = u[ym + x], ud = u[yp + x];
    float vc = v[yr + x], vl = v[yr + xm], vr = v[yr + xp], vu = v[ym + x], vd = v[yp + x];

    float adv_u = uc * (0.5f * (ur - ul)) + vc * (0.5f * (ud - uu));
    float adv_v = uc * (0.5f * (vr - vl)) + vc * (0.5f * (vd - vu));
    float lap_u = ul + ur + uu + ud - 4.0f * uc;
    float lap_v = vl + vr + vu + vd - 4.0f * vc;
    float dpdx = 0.5f * (p[yr + xp] - p[yr + xm]);
    float dpdy = 0.5f * (p[yp + x] - p[ym + x]);

    float sb = sqrtf(beta[b]);
    float fu = F[(size_t)(0 * BB + b) * HW + yr + x];
    float fv = F[(size_t)(1 * BB + b) * HW + yr + x];
    float inu = 1.0f / fmaxf(sqrtf(norms[b]), 1e-12f);
    float inv = 1.0f / fmaxf(sqrtf(norms[BB + b]), 1e-12f);

    float un = uc + 0.01f * (-adv_u + 0.01f * lap_u - dpdx) + sb * fu * inu;
    float vn = vc + 0.01f * (-adv_v + 0.01f * lap_v - dpdy) + sb * fv * inv;

    UV[(size_t)(0 * BB + b) * HW + yr + x] = un;
    UV[(size_t)(1 * BB + b) * HW + yr + x] = vn;
}

// ---------------------------------------------------------------------------
// Divergence, batch-pair packed: D[q] = div(b=2q) + i*div(b=2q+1)
// ---------------------------------------------------------------------------
__global__ __launch_bounds__(256) void k_div2(const float* __restrict__ UV,
                                              float2* __restrict__ D)
{
    int q = blockIdx.z;            // pair 0..3
    int y = blockIdx.y;
    int x = blockIdx.x * 256 + threadIdx.x;
    int yr = y * WW, ym = wrapm(y, HH) * WW, yp = wrapp(y, HH) * WW;
    int xm = wrapm(x, WW), xp = wrapp(x, WW);
    int b0 = 2 * q, b1 = 2 * q + 1;
    const float* u0 = UV + (size_t)b0 * HW;
    const float* v0 = UV + (size_t)(BB + b0) * HW;
    const float* u1 = UV + (size_t)b1 * HW;
    const float* v1 = UV + (size_t)(BB + b1) * HW;
    float d0 = 0.5f * (u0[yr + xp] - u0[yr + xm]) + 0.5f * (v0[yp + x] - v0[ym + x]);
    float d1 = 0.5f * (u1[yr + xp] - u1[yr + xm]) + 0.5f * (v1[yp + x] - v1[ym + x]);
    D[(size_t)q * HW + yr + x] = make_float2(d0, d1);
}

// ---------------------------------------------------------------------------
// FFT helpers (length 1024, LDS, 256 threads)
// ---------------------------------------------------------------------------
static __device__ __forceinline__ void load_tables(const float2* __restrict__ tw,
                                                   float* twr, float* twi)
{
    for (int j = threadIdx.x; j < 1024; j += 256) {
        float2 w = tw[j];
        twr[j] = w.x; twi[j] = w.y;
    }
}

// forward DIF: natural in -> bit-reversed out
static __device__ __forceinline__ void fft_dif(float* re, float* im,
                                               const float* twr, const float* twi)
{
    int t = threadIdx.x;
    for (int s = 9; s >= 0; --s) {
        int len = 1 << s;
        int off = 1024 - 2 * len;
        __syncthreads();
        #pragma unroll
        for (int k = 0; k < 2; ++k) {
            int bt = t + (k << 8);
            int j = bt & (len - 1);
            int i = ((bt >> s) << (s + 1)) | j;
            float ur = re[i], ui = im[i];
            float vr = re[i + len], vi = im[i + len];
            float wr = twr[off + j], wi = twi[off + j];
            re[i] = ur + vr; im[i] = ui + vi;
            float dr = ur - vr, di = ui - vi;
            re[i + len] = dr * wr - di * wi;
            im[i + len] = dr * wi + di * wr;
        }
    }
}

// inverse DIT: bit-reversed in -> natural out (unnormalized)
static __device__ __forceinline__ void fft_dit_inv(float* re, float* im,
                                                   const float* twr, const float* twi)
{
    int t = threadIdx.x;
    for (int s = 0; s <= 9; ++s) {
        int len = 1 << s;
        int off = 1024 - 2 * len;
        __syncthreads();
        #pragma unroll
        for (int k = 0; k < 2; ++k) {
            int bt = t + (k << 8);
            int j = bt & (len - 1);
            int i = ((bt >> s) << (s + 1)) | j;
            float ur = re[i], ui = im[i];
            float vr = re[i + len], vi = im[i + len];
            float wr = twr[off + j], wi = -twi[off + j];
            float tr = vr * wr - vi * wi;
            float ti = vr * wi + vi * wr;
            re[i] = ur + tr;       im[i] = ui + ti;
            re[i + len] = ur - tr; im[i + len] = ui - ti;
        }
    }
}

// Pass A: forward row FFT (natural -> bit-reversed)
__global__ __launch_bounds__(256) void k_fft_fwd(const float2* __restrict__ src,
                                                 float2* __restrict__ dst,
                                                 const float2* __restrict__ tw)
{
    __shared__ float re[1024], im[1024], twr[1024], twi[1024];
    size_t base = (size_t)blockIdx.x * 1024;
    load_tables(tw, twr, twi);
    for (int k = threadIdx.x; k < 1024; k += 256) {
        float2 v = src[base + k]; re[k] = v.x; im[k] = v.y;
    }
    fft_dif(re, im, twr, twi);
    __syncthreads();
    for (int k = threadIdx.x; k < 1024; k += 256) dst[base + k] = make_float2(re[k], im[k]);
}

// Pass B (transposed): col FFT, Poisson scale, inverse col FFT. In place.
__global__ __launch_bounds__(256) void k_fft_poisson(float2* __restrict__ data,
                                                     const float2* __restrict__ tw)
{
    __shared__ float re[1024], im[1024], twr[1024], twi[1024];
    int r = blockIdx.x;
    int i = r & 1023;
    int kx = __brev((unsigned)i) >> 22;
    int fx = (kx < 512) ? kx : kx - 1024;
    float fx2 = (float)(fx * fx);
    size_t base = (size_t)r * 1024;
    load_tables(tw, twr, twi);
    for (int k = threadIdx.x; k < 1024; k += 256) {
        float2 v = data[base + k]; re[k] = v.x; im[k] = v.y;
    }
    fft_dif(re, im, twr, twi);
    __syncthreads();
    const float c = -1.0f / (4.0f * PI_F * PI_F * 1024.0f * 1024.0f); // incl. 1/(H*W)
    for (int k = threadIdx.x; k < 1024; k += 256) {
        int ky = __brev((unsigned)k) >> 22;
        int fy = (ky < 512) ? ky : ky - 1024;
        float k2 = fx2 + (float)(fy * fy);
        float s = (k2 > 0.0f) ? (c / k2) : 0.0f;   // DC zeroed
        re[k] *= s; im[k] *= s;
    }
    fft_dit_inv(re, im, twr, twi);
    __syncthreads();
    for (int k = threadIdx.x; k < 1024; k += 256) data[base + k] = make_float2(re[k], im[k]);
}

// Pass C: inverse row FFT (bit-reversed -> natural)
__global__ __launch_bounds__(256) void k_fft_inv(const float2* __restrict__ src,
                                                 float2* __restrict__ dst,
                                                 const float2* __restrict__ tw)
{
    __shared__ float re[1024], im[1024], twr[1024], twi[1024];
    size_t base = (size_t)blockIdx.x * 1024;
    load_tables(tw, twr, twi);
    for (int k = threadIdx.x; k < 1024; k += 256) {
        float2 v = src[base + k]; re[k] = v.x; im[k] = v.y;
    }
    fft_dit_inv(re, im, twr, twi);
    __syncthreads();
    for (int k = threadIdx.x; k < 1024; k += 256) dst[base + k] = make_float2(re[k], im[k]);
}

// ---------------------------------------------------------------------------
// Per-image complex transpose, 32x32 tiles (4 packed images)
// ---------------------------------------------------------------------------
__global__ __launch_bounds__(256) void k_transpose(const float2* __restrict__ src,
                                                   float2* __restrict__ dst)
{
    __shared__ float2 tile[32][33];
    size_t ib = (size_t)blockIdx.z * (size_t)HW;
    int x = blockIdx.x * 32 + threadIdx.x;
    int y0 = blockIdx.y * 32 + threadIdx.y;
    #pragma unroll
    for (int k = 0; k < 4; ++k)
        tile[threadIdx.y + 8 * k][threadIdx.x] = src[ib + (size_t)(y0 + 8 * k) * WW + x];
    __syncthreads();
    int x2 = blockIdx.y * 32 + threadIdx.x;
    int y2 = blockIdx.x * 32 + threadIdx.y;
    #pragma unroll
    for (int k = 0; k < 4; ++k)
        dst[ib + (size_t)(y2 + 8 * k) * WW + x2] = tile[threadIdx.x][threadIdx.y + 8 * k];
}

// ---------------------------------------------------------------------------
// Final projection + output stack (PC packed per batch-pair)
// ---------------------------------------------------------------------------
__global__ __launch_bounds__(256) void k_final(const float* __restrict__ UV,
                                               const float* __restrict__ X,
                                               const float2* __restrict__ PC,
                                               float* __restrict__ out)
{
    int b = blockIdx.z;
    int q = b >> 1, comp = b & 1;
    int y = blockIdx.y;
    int x = blockIdx.x * 256 + threadIdx.x;
    int yr = y * WW, ym = wrapm(y, HH) * WW, yp = wrapp(y, HH) * WW;
    int xm = wrapm(x, WW), xp = wrapp(x, WW);
    const float2* pc = PC + (size_t)q * HW;
    float2 pxp = pc[yr + xp], pxm = pc[yr + xm];
    float2 pyp = pc[yp + x],  pym = pc[ym + x];
    float2 pcc = pc[yr + x];
    float gx, gy, pv;
    if (comp == 0) { gx = 0.5f * (pxp.x - pxm.x); gy = 0.5f * (pyp.x - pym.x); pv = pcc.x; }
    else           { gx = 0.5f * (pxp.y - pxm.y); gy = 0.5f * (pyp.y - pym.y); pv = pcc.y; }
    float un = UV[(size_t)(0 * BB + b) * HW + yr + x] - gx;
    float vn = UV[(size_t)(1 * BB + b) * HW + yr + x] - gy;
    float pn = X[(size_t)(b * 3 + 2) * HW + yr + x] + pv;
    out[(size_t)(b * 3 + 0) * HW + yr + x] = un;
    out[(size_t)(b * 3 + 1) * HW + yr + x] = vn;
    out[(size_t)(b * 3 + 2) * HW + yr + x] = pn;
}

extern "C" void kernel_launch(void* const* d_in, const int* in_sizes, int n_in,
                              void* d_out, int out_size, void* d_ws, size_t ws_size,
                              hipStream_t stream)
{
    const float* X    = (const float*)d_in[0];
    const float* beta = (const float*)d_in[1];
    const float* fu   = (const float*)d_in[2];
    const float* fv   = (const float*)d_in[3];
    float* out = (float*)d_out;
    float* ws  = (float*)d_ws;

    float* F1  = ws;                              // 16M floats (64MB)
    float* UV  = F1 + (size_t)2 * BB * HW;        // 16M floats (64MB)
    float* Dpf = UV + (size_t)2 * BB * HW;        // 8M floats  (32MB, 4 complex imgs)
    float* Cbf = Dpf + (size_t)BB * HW;           // 8M floats  (32MB)
    float* TWf = Cbf + (size_t)BB * HW;           // 2048 floats
    float* NRM = TWf + 2048;                      // 16 floats
    float2* Dp = (float2*)Dpf;
    float2* Cb = (float2*)Cbf;
    float2* TW = (float2*)TWf;

    (void)hipMemsetAsync(NRM, 0, 16 * sizeof(float), stream);
    k_twid<<<4, 256, 0, stream>>>(TW);

    dim3 blk(256);
    dim3 gridD(WW / TDX, HH / TDY, 2 * BB);       // 16 x 32 x 16
    dim3 gridB(WW / 256, HH, BB);
    dim3 gridQ(WW / 256, HH, BB / 2);
    dim3 tgrid(32, 32, BB / 2), tblk(32, 8);

    k_diff3<<<gridD, blk, 0, stream>>>(fu, fv, F1, NRM);
    k_star<<<gridB, blk, 0, stream>>>(X, beta, F1, NRM, UV);
    k_div2<<<gridQ, blk, 0, stream>>>(UV, Dp);

    k_fft_fwd<<<(BB / 2) * HH, blk, 0, stream>>>(Dp, Cb, TW);
    k_transpose<<<tgrid, tblk, 0, stream>>>(Cb, Dp);
    k_fft_poisson<<<(BB / 2) * HH, blk, 0, stream>>>(Dp, TW);
    k_transpose<<<tgrid, tblk, 0, stream>>>(Dp, Cb);
    k_fft_inv<<<(BB / 2) * HH, blk, 0, stream>>>(Cb, Dp, TW);

    k_final<<<gridB, blk, 0, stream>>>(UV, X, Dp, out);
}

// Round 2
// 284.262 us; speedup vs baseline: 1.3335x; 1.2655x over previous
//
#include <hip/hip_runtime.h>

#define BB 8
#define HH 1024
#define WW 1024
#define HW (HH*WW)
#define PI_F 3.14159265358979323846f

static __device__ __forceinline__ int wrapm(int i, int n) { return (i == 0) ? n - 1 : i - 1; }
static __device__ __forceinline__ int wrapp(int i, int n) { return (i == n - 1) ? 0 : i + 1; }

// ---------------------------------------------------------------------------
// Twiddle table (global, computed once per launch): per-stage concatenated,
// stage with half-span len at offset (1024-2*len), len entries exp(-i*pi*j/len)
// ---------------------------------------------------------------------------
__global__ __launch_bounds__(256) void k_twid(float2* __restrict__ tw)
{
    int tid = blockIdx.x * 256 + threadIdx.x;   // grid 4x256 = 1024 threads
    for (int len = 512; len >= 1; len >>= 1) {
        int off = 1024 - 2 * len;
        float fac = -PI_F / (float)len;
        for (int j = tid; j < len; j += 1024) {
            float sn, cs;
            sincosf(fac * (float)j, &sn, &cs);
            tw[off + j] = make_float2(cs, sn);
        }
    }
}

// ---------------------------------------------------------------------------
// Fused 3x diffusion of f_u/f_v + L2 norm — full-width band register-march.
// Block: 256 threads, each owns quad q (x = 4q) of the 1024-wide row.
// Band: 8 output rows; raw band 14 rows (halo 3+3) staged to LDS by DMA.
// One barrier total. Each thread marches rows keeping rolling 3-row windows:
// raw 12-wide, iter1 8-wide, iter2 6-wide (x-halo recomputed, no cross-lane
// traffic). Reads: 3 aligned ds_read_b128/row, wave-contiguous (conflict-
// free), row offset is a compile-time immediate. Fully unrolled.
// dst layout [f*8+b][HW]; grid 2048 blocks = 16 z * 128 bands, XCD-swizzled.
// ---------------------------------------------------------------------------
#define RBAND 8
#define RAWROWS 14          // RBAND + 6

static __device__ __forceinline__ void gload16(const float* g, float* l)
{
    __builtin_amdgcn_global_load_lds(
        (const __attribute__((address_space(1))) void*)g,
        (__attribute__((address_space(3))) void*)l,
        16, 0, 0);
}

__global__ __launch_bounds__(256) void k_diff3(const float* __restrict__ su,
                                               const float* __restrict__ sv,
                                               float* __restrict__ dst,
                                               float* __restrict__ norms)
{
    __shared__ __align__(16) float A[RAWROWS * WW];   // 56 KB
    __shared__ float wsum[4];

    // bijective XCD swizzle (nwg = 2048, divisible by 8): each XCD gets 256
    // consecutive works = 2 whole images of consecutive bands -> halo rows L2-hit
    int bid = blockIdx.x;
    int work = (bid & 7) * 256 + (bid >> 3);
    int z = work >> 7;            // f*8+b, 0..15
    int band = work & 127;
    int f = z >> 3, b = z & 7;
    const float* s = ((f == 0) ? su : sv) + (size_t)b * HW;
    float* d = dst + (size_t)z * HW;
    int yb = band * RBAND;
    int tid = threadIdx.x;
    int w = tid >> 6, lane = tid & 63;

    // ---- DMA stage: 56 chunks of 1KB (64 lanes x 16B), contiguous ---------
    for (int c = w; c < RAWROWS * 4; c += 4) {
        int row = c >> 2, seg = c & 3;
        const float* g = s + (size_t)((yb - 3 + row) & (HH - 1)) * WW
                           + (seg << 8) + (lane << 2);
        gload16(g, &A[(c << 8) + (lane << 2)]);
    }
    __syncthreads();   // drains vmcnt(0)

    // per-thread byte offsets within a row (x-wrap via & 4095)
    const char* Ab = (const char*)A;
    int xq = tid << 4;
    int om = (xq - 16) & 4095;
    int op = (xq + 16) & 4095;

    float r[3][12];    // raw window, x0-4 .. x0+7
    float i1[3][8];    // iter1 window, x0-2 .. x0+5
    float i2[3][6];    // iter2 window, x0-1 .. x0+4
    float sq = 0.0f;

    #pragma unroll
    for (int j = 0; j < RAWROWS; ++j) {
        // load raw row j (12 floats: quads q-1, q, q+1)
        {
            float4 a = *(const float4*)(Ab + j * 4096 + om);
            float4 bq = *(const float4*)(Ab + j * 4096 + xq);
            float4 cq = *(const float4*)(Ab + j * 4096 + op);
            float* rr = r[j % 3];
            rr[0] = a.x; rr[1] = a.y; rr[2] = a.z; rr[3] = a.w;
            rr[4] = bq.x; rr[5] = bq.y; rr[6] = bq.z; rr[7] = bq.w;
            rr[8] = cq.x; rr[9] = cq.y; rr[10] = cq.z; rr[11] = cq.w;
        }
        // iter1 at raw row t = j-1 (8 wide)
        if (j >= 2) {
            const float* ru = r[(j - 2) % 3];
            const float* rc = r[(j - 1) % 3];
            const float* rd = r[j % 3];
            float* o = i1[(j - 1) % 3];
            #pragma unroll
            for (int k = 0; k < 8; ++k) {
                float c0 = rc[k + 2];
                o[k] = c0 + 0.1f * (rc[k + 1] + rc[k + 3] + ru[k + 2] + rd[k + 2] - 4.0f * c0);
            }
        }
        // iter2 at row t = j-2 (6 wide)
        if (j >= 4) {
            const float* u = i1[(j - 3) % 3];
            const float* c = i1[(j - 2) % 3];
            const float* dd = i1[(j - 1) % 3];
            float* o = i2[(j - 2) % 3];
            #pragma unroll
            for (int k = 0; k < 6; ++k) {
                float c0 = c[k + 1];
                o[k] = c0 + 0.1f * (c[k] + c[k + 2] + u[k + 1] + dd[k + 1] - 4.0f * c0);
            }
        }
        // iter3 + store at row t = j-3 (4 wide), valid for j >= 6
        if (j >= 6) {
            const float* u = i2[(j - 4) % 3];
            const float* c = i2[(j - 3) % 3];
            const float* dd = i2[(j - 2) % 3];
            float4 o;
            float* op4 = (float*)&o;
            #pragma unroll
            for (int k = 0; k < 4; ++k) {
                float c0 = c[k + 1];
                op4[k] = c0 + 0.1f * (c[k] + c[k + 2] + u[k + 1] + dd[k + 1] - 4.0f * c0);
            }
            *(float4*)(d + (size_t)(yb + j - 6) * WW + (tid << 2)) = o;
            sq += o.x * o.x + o.y * o.y + o.z * o.z + o.w * o.w;
        }
    }

    #pragma unroll
    for (int o = 32; o > 0; o >>= 1) sq += __shfl_down(sq, o, 64);
    if (lane == 0) wsum[w] = sq;
    __syncthreads();
    if (tid == 0)
        atomicAdd(&norms[z], wsum[0] + wsum[1] + wsum[2] + wsum[3]);
}

// ---------------------------------------------------------------------------
// Star velocities
// ---------------------------------------------------------------------------
__global__ __launch_bounds__(256) void k_star(const float* __restrict__ X,
                                              const float* __restrict__ beta,
                                              const float* __restrict__ F,
                                              const float* __restrict__ norms,
                                              float* __restrict__ UV)
{
    int b = blockIdx.z;
    int y = blockIdx.y;
    int x = blockIdx.x * 256 + threadIdx.x;
    const float* u = X + (size_t)(b * 3 + 0) * HW;
    const float* v = X + (size_t)(b * 3 + 1) * HW;
    const float* p = X + (size_t)(b * 3 + 2) * HW;
    int yr = y * WW, ym = wrapm(y, HH) * WW, yp = wrapp(y, HH) * WW;
    int xm = wrapm(x, WW), xp = wrapp(x, WW);

    float uc = u[yr + x], ul = u[yr + xm], ur = u[yr + xp], uu = u[ym + x], ud = u[yp + x];
    float vc = v[yr + x], vl = v[yr + xm], vr = v[yr + xp], vu = v[ym + x], vd = v[yp + x];

    float adv_u = uc * (0.5f * (ur - ul)) + vc * (0.5f * (ud - uu));
    float adv_v = uc * (0.5f * (vr - vl)) + vc * (0.5f * (vd - vu));
    float lap_u = ul + ur + uu + ud - 4.0f * uc;
    float lap_v = vl + vr + vu + vd - 4.0f * vc;
    float dpdx = 0.5f * (p[yr + xp] - p[yr + xm]);
    float dpdy = 0.5f * (p[yp + x] - p[ym + x]);

    float sb = sqrtf(beta[b]);
    float fu = F[(size_t)(0 * BB + b) * HW + yr + x];
    float fv = F[(size_t)(1 * BB + b) * HW + yr + x];
    float inu = 1.0f / fmaxf(sqrtf(norms[b]), 1e-12f);
    float inv = 1.0f / fmaxf(sqrtf(norms[BB + b]), 1e-12f);

    float un = uc + 0.01f * (-adv_u + 0.01f * lap_u - dpdx) + sb * fu * inu;
    float vn = vc + 0.01f * (-adv_v + 0.01f * lap_v - dpdy) + sb * fv * inv;

    UV[(size_t)(0 * BB + b) * HW + yr + x] = un;
    UV[(size_t)(1 * BB + b) * HW + yr + x] = vn;
}

// ---------------------------------------------------------------------------
// Divergence, batch-pair packed: D[q] = div(b=2q) + i*div(b=2q+1)
// ---------------------------------------------------------------------------
__global__ __launch_bounds__(256) void k_div2(const float* __restrict__ UV,
                                              float2* __restrict__ D)
{
    int q = blockIdx.z;            // pair 0..3
    int y = blockIdx.y;
    int x = blockIdx.x * 256 + threadIdx.x;
    int yr = y * WW, ym = wrapm(y, HH) * WW, yp = wrapp(y, HH) * WW;
    int xm = wrapm(x, WW), xp = wrapp(x, WW);
    int b0 = 2 * q, b1 = 2 * q + 1;
    const float* u0 = UV + (size_t)b0 * HW;
    const float* v0 = UV + (size_t)(BB + b0) * HW;
    const float* u1 = UV + (size_t)b1 * HW;
    const float* v1 = UV + (size_t)(BB + b1) * HW;
    float d0 = 0.5f * (u0[yr + xp] - u0[yr + xm]) + 0.5f * (v0[yp + x] - v0[ym + x]);
    float d1 = 0.5f * (u1[yr + xp] - u1[yr + xm]) + 0.5f * (v1[yp + x] - v1[ym + x]);
    D[(size_t)q * HW + yr + x] = make_float2(d0, d1);
}

// ---------------------------------------------------------------------------
// FFT helpers (length 1024, LDS, 256 threads)
// ---------------------------------------------------------------------------
static __device__ __forceinline__ void load_tables(const float2* __restrict__ tw,
                                                   float* twr, float* twi)
{
    for (int j = threadIdx.x; j < 1024; j += 256) {
        float2 w = tw[j];
        twr[j] = w.x; twi[j] = w.y;
    }
}

// forward DIF: natural in -> bit-reversed out
static __device__ __forceinline__ void fft_dif(float* re, float* im,
                                               const float* twr, const float* twi)
{
    int t = threadIdx.x;
    for (int s = 9; s >= 0; --s) {
        int len = 1 << s;
        int off = 1024 - 2 * len;
        __syncthreads();
        #pragma unroll
        for (int k = 0; k < 2; ++k) {
            int bt = t + (k << 8);
            int j = bt & (len - 1);
            int i = ((bt >> s) << (s + 1)) | j;
            float ur = re[i], ui = im[i];
            float vr = re[i + len], vi = im[i + len];
            float wr = twr[off + j], wi = twi[off + j];
            re[i] = ur + vr; im[i] = ui + vi;
            float dr = ur - vr, di = ui - vi;
            re[i + len] = dr * wr - di * wi;
            im[i + len] = dr * wi + di * wr;
        }
    }
}

// inverse DIT: bit-reversed in -> natural out (unnormalized)
static __device__ __forceinline__ void fft_dit_inv(float* re, float* im,
                                                   const float* twr, const float* twi)
{
    int t = threadIdx.x;
    for (int s = 0; s <= 9; ++s) {
        int len = 1 << s;
        int off = 1024 - 2 * len;
        __syncthreads();
        #pragma unroll
        for (int k = 0; k < 2; ++k) {
            int bt = t + (k << 8);
            int j = bt & (len - 1);
            int i = ((bt >> s) << (s + 1)) | j;
            float ur = re[i], ui = im[i];
            float vr = re[i + len], vi = im[i + len];
            float wr = twr[off + j], wi = -twi[off + j];
            float tr = vr * wr - vi * wi;
            float ti = vr * wi + vi * wr;
            re[i] = ur + tr;       im[i] = ui + ti;
            re[i + len] = ur - tr; im[i + len] = ui - ti;
        }
    }
}

// Pass A: forward row FFT (natural -> bit-reversed)
__global__ __launch_bounds__(256) void k_fft_fwd(const float2* __restrict__ src,
                                                 float2* __restrict__ dst,
                                                 const float2* __restrict__ tw)
{
    __shared__ float re[1024], im[1024], twr[1024], twi[1024];
    size_t base = (size_t)blockIdx.x * 1024;
    load_tables(tw, twr, twi);
    for (int k = threadIdx.x; k < 1024; k += 256) {
        float2 v = src[base + k]; re[k] = v.x; im[k] = v.y;
    }
    fft_dif(re, im, twr, twi);
    __syncthreads();
    for (int k = threadIdx.x; k < 1024; k += 256) dst[base + k] = make_float2(re[k], im[k]);
}

// Pass B (transposed): col FFT, Poisson scale, inverse col FFT. In place.
__global__ __launch_bounds__(256) void k_fft_poisson(float2* __restrict__ data,
                                                     const float2* __restrict__ tw)
{
    __shared__ float re[1024], im[1024], twr[1024], twi[1024];
    int r = blockIdx.x;
    int i = r & 1023;
    int kx = __brev((unsigned)i) >> 22;
    int fx = (kx < 512) ? kx : kx - 1024;
    float fx2 = (float)(fx * fx);
    size_t base = (size_t)r * 1024;
    load_tables(tw, twr, twi);
    for (int k = threadIdx.x; k < 1024; k += 256) {
        float2 v = data[base + k]; re[k] = v.x; im[k] = v.y;
    }
    fft_dif(re, im, twr, twi);
    __syncthreads();
    const float c = -1.0f / (4.0f * PI_F * PI_F * 1024.0f * 1024.0f); // incl. 1/(H*W)
    for (int k = threadIdx.x; k < 1024; k += 256) {
        int ky = __brev((unsigned)k) >> 22;
        int fy = (ky < 512) ? ky : ky - 1024;
        float k2 = fx2 + (float)(fy * fy);
        float s = (k2 > 0.0f) ? (c / k2) : 0.0f;   // DC zeroed
        re[k] *= s; im[k] *= s;
    }
    fft_dit_inv(re, im, twr, twi);
    __syncthreads();
    for (int k = threadIdx.x; k < 1024; k += 256) data[base + k] = make_float2(re[k], im[k]);
}

// Pass C: inverse row FFT (bit-reversed -> natural)
__global__ __launch_bounds__(256) void k_fft_inv(const float2* __restrict__ src,
                                                 float2* __restrict__ dst,
                                                 const float2* __restrict__ tw)
{
    __shared__ float re[1024], im[1024], twr[1024], twi[1024];
    size_t base = (size_t)blockIdx.x * 1024;
    load_tables(tw, twr, twi);
    for (int k = threadIdx.x; k < 1024; k += 256) {
        float2 v = src[base + k]; re[k] = v.x; im[k] = v.y;
    }
    fft_dit_inv(re, im, twr, twi);
    __syncthreads();
    for (int k = threadIdx.x; k < 1024; k += 256) dst[base + k] = make_float2(re[k], im[k]);
}

// ---------------------------------------------------------------------------
// Per-image complex transpose, 32x32 tiles (4 packed images)
// ---------------------------------------------------------------------------
__global__ __launch_bounds__(256) void k_transpose(const float2* __restrict__ src,
                                                   float2* __restrict__ dst)
{
    __shared__ float2 tile[32][33];
    size_t ib = (size_t)blockIdx.z * (size_t)HW;
    int x = blockIdx.x * 32 + threadIdx.x;
    int y0 = blockIdx.y * 32 + threadIdx.y;
    #pragma unroll
    for (int k = 0; k < 4; ++k)
        tile[threadIdx.y + 8 * k][threadIdx.x] = src[ib + (size_t)(y0 + 8 * k) * WW + x];
    __syncthreads();
    int x2 = blockIdx.y * 32 + threadIdx.x;
    int y2 = blockIdx.x * 32 + threadIdx.y;
    #pragma unroll
    for (int k = 0; k < 4; ++k)
        dst[ib + (size_t)(y2 + 8 * k) * WW + x2] = tile[threadIdx.x][threadIdx.y + 8 * k];
}

// ---------------------------------------------------------------------------
// Final projection + output stack (PC packed per batch-pair)
// ---------------------------------------------------------------------------
__global__ __launch_bounds__(256) void k_final(const float* __restrict__ UV,
                                               const float* __restrict__ X,
                                               const float2* __restrict__ PC,
                                               float* __restrict__ out)
{
    int b = blockIdx.z;
    int q = b >> 1, comp = b & 1;
    int y = blockIdx.y;
    int x = blockIdx.x * 256 + threadIdx.x;
    int yr = y * WW, ym = wrapm(y, HH) * WW, yp = wrapp(y, HH) * WW;
    int xm = wrapm(x, WW), xp = wrapp(x, WW);
    const float2* pc = PC + (size_t)q * HW;
    float2 pxp = pc[yr + xp], pxm = pc[yr + xm];
    float2 pyp = pc[yp + x],  pym = pc[ym + x];
    float2 pcc = pc[yr + x];
    float gx, gy, pv;
    if (comp == 0) { gx = 0.5f * (pxp.x - pxm.x); gy = 0.5f * (pyp.x - pym.x); pv = pcc.x; }
    else           { gx = 0.5f * (pxp.y - pxm.y); gy = 0.5f * (pyp.y - pym.y); pv = pcc.y; }
    float un = UV[(size_t)(0 * BB + b) * HW + yr + x] - gx;
    float vn = UV[(size_t)(1 * BB + b) * HW + yr + x] - gy;
    float pn = X[(size_t)(b * 3 + 2) * HW + yr + x] + pv;
    out[(size_t)(b * 3 + 0) * HW + yr + x] = un;
    out[(size_t)(b * 3 + 1) * HW + yr + x] = vn;
    out[(size_t)(b * 3 + 2) * HW + yr + x] = pn;
}

extern "C" void kernel_launch(void* const* d_in, const int* in_sizes, int n_in,
                              void* d_out, int out_size, void* d_ws, size_t ws_size,
                              hipStream_t stream)
{
    const float* X    = (const float*)d_in[0];
    const float* beta = (const float*)d_in[1];
    const float* fu   = (const float*)d_in[2];
    const float* fv   = (const float*)d_in[3];
    float* out = (float*)d_out;
    float* ws  = (float*)d_ws;

    float* F1  = ws;                              // 16M floats (64MB)
    float* UV  = F1 + (size_t)2 * BB * HW;        // 16M floats (64MB)
    float* Dpf = UV + (size_t)2 * BB * HW;        // 8M floats  (32MB, 4 complex imgs)
    float* Cbf = Dpf + (size_t)BB * HW;           // 8M floats  (32MB)
    float* TWf = Cbf + (size_t)BB * HW;           // 2048 floats
    float* NRM = TWf + 2048;                      // 16 floats
    float2* Dp = (float2*)Dpf;
    float2* Cb = (float2*)Cbf;
    float2* TW = (float2*)TWf;

    (void)hipMemsetAsync(NRM, 0, 16 * sizeof(float), stream);
    k_twid<<<4, 256, 0, stream>>>(TW);

    dim3 blk(256);
    dim3 gridB(WW / 256, HH, BB);
    dim3 gridQ(WW / 256, HH, BB / 2);
    dim3 tgrid(32, 32, BB / 2), tblk(32, 8);

    k_diff3<<<2048, blk, 0, stream>>>(fu, fv, F1, NRM);
    k_star<<<gridB, blk, 0, stream>>>(X, beta, F1, NRM, UV);
    k_div2<<<gridQ, blk, 0, stream>>>(UV, Dp);

    k_fft_fwd<<<(BB / 2) * HH, blk, 0, stream>>>(Dp, Cb, TW);
    k_transpose<<<tgrid, tblk, 0, stream>>>(Cb, Dp);
    k_fft_poisson<<<(BB / 2) * HH, blk, 0, stream>>>(Dp, TW);
    k_transpose<<<tgrid, tblk, 0, stream>>>(Dp, Cb);
    k_fft_inv<<<(BB / 2) * HH, blk, 0, stream>>>(Cb, Dp, TW);

    k_final<<<gridB, blk, 0, stream>>>(UV, X, Dp, out);
}